// Round 1
// baseline (4453.803 us; speedup 1.0000x reference)
//
#include <hip/hip_runtime.h>

#define NB 32
#define NK 8
#define NBOOK 1024
#define NCH 256
#define NPTS 256
#define NTOT (NB*NPTS)          // 8192
#define TINV 2.0f               // 1/TEMP
#define GEPS 1e-10f

#define ZQ_ELEMS   2097152      // 32*256*16*16
#define PREC_OFF   2097152
#define PROB_OFF   2097153
#define LPROB_OFF  10485761     // PROB_OFF + 32*256*1024

static __device__ __forceinline__ float gumbelf(float u) {
    return -__logf(-__logf(u + GEPS) + GEPS);
}

// ---------- prep: c_probs (ws[0..255]), precision_q (ws[256]), book_sq (ws[512..8703]) ----------
__global__ __launch_bounds__(256)
void prep_kernel(const float* __restrict__ c_logits,
                 const float* __restrict__ u_cls,
                 const float* __restrict__ books,
                 const float* __restrict__ log_param_q,
                 const float* __restrict__ log_param_q_cls,
                 float* __restrict__ ws,
                 float* __restrict__ out_prec)
{
    int g = blockIdx.x * 256 + threadIdx.x;     // 0..8191 == k*1024 + j
    const float* bp = books + (size_t)g * NCH;
    float s = 0.f;
    #pragma unroll
    for (int c4 = 0; c4 < NCH/4; ++c4) {
        float4 v = *(const float4*)(bp + c4*4);
        s += v.x*v.x + v.y*v.y + v.z*v.z + v.w*v.w;
    }
    ws[512 + g] = s;

    if (blockIdx.x == 0) {
        int t = threadIdx.x;
        if (t == 0) {
            float pq = 1.0f + __expf(log_param_q[0]);
            float prec = 0.5f / fmaxf(pq, 1e-10f);
            ws[256] = prec;
            out_prec[0] = prec;
        }
        if (t < NB) {
            float pc = 0.5f / fmaxf(1.0f + __expf(log_param_q_cls[0]), 1e-10f);
            float x[NK]; float mx = -1e30f;
            #pragma unroll
            for (int k = 0; k < NK; ++k) {
                x[k] = (c_logits[t*NK+k]*pc + gumbelf(u_cls[t*NK+k])) * TINV;
                mx = fmaxf(mx, x[k]);
            }
            float ssum = 0.f;
            #pragma unroll
            for (int k = 0; k < NK; ++k) { x[k] = __expf(x[k]-mx); ssum += x[k]; }
            float inv = 1.f/ssum;
            #pragma unroll
            for (int k = 0; k < NK; ++k) ws[t*NK+k] = x[k]*inv;
        }
    }
}

// ---------- main fused kernel: one block = 16 consecutive n rows ----------
__global__ __launch_bounds__(256, 2)
void vq_main(const float* __restrict__ ze,
             const float* __restrict__ u_enc,
             const float* __restrict__ books,
             const float* __restrict__ ws,
             float* __restrict__ out)
{
    __shared__ float ze_lds[16][NCH];       // 16 KB
    __shared__ float enc_lds[16][NBOOK];    // 64 KB

    const int t  = threadIdx.x;
    const int l  = t & 63;
    const int w  = t >> 6;
    const int n0 = blockIdx.x * 16;
    const int b  = n0 >> 8;
    const int p0 = n0 & 255;

    const float prec = ws[256];

    // ze tile: ze_flat[n][c] = ze[b*65536 + c*256 + p], p = p0 + m
    {
        const float* zb = ze + (size_t)b*65536 + p0;
        #pragma unroll
        for (int it = 0; it < 16; ++it) {
            int idx = it*256 + t;
            int c = idx >> 4, m = idx & 15;
            ze_lds[m][c] = zb[c*256 + m];
        }
    }
    __syncthreads();

    // |ze_row|^2 for this wave's 4 rows
    float zsq[4];
    #pragma unroll
    for (int r = 0; r < 4; ++r) {
        float s = 0.f;
        for (int c4 = 0; c4 < NCH/4; ++c4) {
            float4 z = *(const float4*)&ze_lds[w*4+r][c4*4];
            s += z.x*z.x + z.y*z.y + z.z*z.z + z.w*z.w;
        }
        zsq[r] = s;
    }

    float mix[4][16], lg[4][16], zq_acc[16];
    #pragma unroll
    for (int r = 0; r < 4; ++r)
        #pragma unroll
        for (int jj = 0; jj < 16; ++jj) mix[r][jj] = 0.f;
    #pragma unroll
    for (int q = 0; q < 16; ++q) zq_acc[q] = 0.f;

    const int m2 = t >> 4;      // GEMM2 row
    const int cb = t & 15;      // GEMM2 col block (16 floats)

    for (int k = 0; k < NK; ++k) {
        const float cp = ws[b*NK + k];
        const float* bk = books + (size_t)k*NBOOK*NCH;

        // ---- GEMM1: cross products, lane l owns j = jj*64 + l ----
        #pragma unroll
        for (int r = 0; r < 4; ++r)
            #pragma unroll
            for (int jj = 0; jj < 16; ++jj) lg[r][jj] = 0.f;

        for (int c4 = 0; c4 < NCH/4; ++c4) {
            float4 z0 = *(const float4*)&ze_lds[w*4+0][c4*4];
            float4 z1 = *(const float4*)&ze_lds[w*4+1][c4*4];
            float4 z2 = *(const float4*)&ze_lds[w*4+2][c4*4];
            float4 z3 = *(const float4*)&ze_lds[w*4+3][c4*4];
            const float* bc = bk + l*NCH + c4*4;
            #pragma unroll
            for (int jj = 0; jj < 16; ++jj) {
                float4 v = *(const float4*)(bc + jj*64*NCH);
                lg[0][jj] += z0.x*v.x + z0.y*v.y + z0.z*v.z + z0.w*v.w;
                lg[1][jj] += z1.x*v.x + z1.y*v.y + z1.z*v.z + z1.w*v.w;
                lg[2][jj] += z2.x*v.x + z2.y*v.y + z2.z*v.z + z2.w*v.w;
                lg[3][jj] += z3.x*v.x + z3.y*v.y + z3.z*v.z + z3.w*v.w;
            }
        }

        // ---- logits_k, mixture accumulation, gumbel-softmax (enc) ----
        float bsq[16];
        #pragma unroll
        for (int jj = 0; jj < 16; ++jj) bsq[jj] = ws[512 + k*NBOOK + jj*64 + l];

        const float* up = u_enc + ((size_t)k*NTOT + n0)*NBOOK + l;
        float sc[4];
        #pragma unroll
        for (int r = 0; r < 4; ++r) {
            float mx = -1e30f;
            #pragma unroll
            for (int jj = 0; jj < 16; ++jj) {
                float lgv = -(zsq[r] + bsq[jj] - 2.f*lg[r][jj]) * prec;
                mix[r][jj] += cp * lgv;
                float x = (lgv + gumbelf(up[(size_t)(w*4+r)*NBOOK + jj*64])) * TINV;
                lg[r][jj] = x;
                mx = fmaxf(mx, x);
            }
            #pragma unroll
            for (int o = 32; o >= 1; o >>= 1) mx = fmaxf(mx, __shfl_xor(mx, o));
            float ssum = 0.f;
            #pragma unroll
            for (int jj = 0; jj < 16; ++jj) { float e = __expf(lg[r][jj]-mx); lg[r][jj] = e; ssum += e; }
            #pragma unroll
            for (int o = 32; o >= 1; o >>= 1) ssum += __shfl_xor(ssum, o);
            sc[r] = cp / ssum;   // premultiply cluster prob / softmax denom
        }

        __syncthreads();   // previous GEMM2 done reading enc_lds
        #pragma unroll
        for (int r = 0; r < 4; ++r)
            #pragma unroll
            for (int jj = 0; jj < 16; ++jj)
                enc_lds[w*4+r][jj*64+l] = lg[r][jj]*sc[r];
        __syncthreads();   // enc tile ready

        // ---- GEMM2: zq_acc[m2][cb*16..+15] += enc * books (skip near-zero rows) ----
        const float* bk2 = bk + cb*16;
        for (int j = 0; j < NBOOK; ++j) {
            float ev = enc_lds[m2][j];
            if (!__any(ev > 1e-8f)) continue;
            const float* bj = bk2 + (size_t)j*NCH;
            float4 v0 = *(const float4*)(bj+0);
            float4 v1 = *(const float4*)(bj+4);
            float4 v2 = *(const float4*)(bj+8);
            float4 v3 = *(const float4*)(bj+12);
            zq_acc[ 0] += ev*v0.x; zq_acc[ 1] += ev*v0.y; zq_acc[ 2] += ev*v0.z; zq_acc[ 3] += ev*v0.w;
            zq_acc[ 4] += ev*v1.x; zq_acc[ 5] += ev*v1.y; zq_acc[ 6] += ev*v1.z; zq_acc[ 7] += ev*v1.w;
            zq_acc[ 8] += ev*v2.x; zq_acc[ 9] += ev*v2.y; zq_acc[10] += ev*v2.z; zq_acc[11] += ev*v2.w;
            zq_acc[12] += ev*v3.x; zq_acc[13] += ev*v3.y; zq_acc[14] += ev*v3.z; zq_acc[15] += ev*v3.w;
        }
    }

    // ---- mixture softmax -> prob / log_prob ----
    #pragma unroll
    for (int r = 0; r < 4; ++r) {
        int n = n0 + w*4 + r;
        float mx = -1e30f;
        #pragma unroll
        for (int jj = 0; jj < 16; ++jj) mx = fmaxf(mx, mix[r][jj]);
        #pragma unroll
        for (int o = 32; o >= 1; o >>= 1) mx = fmaxf(mx, __shfl_xor(mx, o));
        float ssum = 0.f;
        #pragma unroll
        for (int jj = 0; jj < 16; ++jj) ssum += __expf(mix[r][jj]-mx);
        #pragma unroll
        for (int o = 32; o >= 1; o >>= 1) ssum += __shfl_xor(ssum, o);
        float inv = 1.f/ssum;
        float ls  = __logf(ssum);
        float* pp = out + PROB_OFF  + (size_t)n*NBOOK;
        float* lp = out + LPROB_OFF + (size_t)n*NBOOK;
        #pragma unroll
        for (int jj = 0; jj < 16; ++jj) {
            float xm = mix[r][jj] - mx;
            pp[jj*64+l] = __expf(xm)*inv;
            lp[jj*64+l] = xm - ls;
        }
    }

    // ---- zq store: out[b][c][p] ----
    {
        float* zo = out + (size_t)b*65536 + p0 + m2;
        #pragma unroll
        for (int q = 0; q < 16; ++q)
            zo[(size_t)(cb*16+q)*256] = zq_acc[q];
    }
}

extern "C" void kernel_launch(void* const* d_in, const int* in_sizes, int n_in,
                              void* d_out, int out_size, void* d_ws, size_t ws_size,
                              hipStream_t stream)
{
    (void)in_sizes; (void)n_in; (void)out_size; (void)ws_size;
    const float* ze       = (const float*)d_in[0];
    const float* c_logits = (const float*)d_in[1];
    const float* u_cls    = (const float*)d_in[2];
    const float* u_enc    = (const float*)d_in[3];
    const float* books    = (const float*)d_in[4];
    const float* lq       = (const float*)d_in[5];
    const float* lqc      = (const float*)d_in[6];
    float* out = (float*)d_out;
    float* ws  = (float*)d_ws;

    prep_kernel<<<32, 256, 0, stream>>>(c_logits, u_cls, books, lq, lqc, ws, out + PREC_OFF);
    vq_main<<<512, 256, 0, stream>>>(ze, u_enc, books, ws, out);
}